// Round 1
// baseline (892.416 us; speedup 1.0000x reference)
//
#include <hip/hip_runtime.h>
#include <hip/hip_bf16.h>
#include <stdint.h>

#define Bb 8
#define Ss 2048
#define Dd 4096
#define Ee 64
#define CAP 40
#define M_TOK (Bb*Ss)                   // 16384 tokens
#define NBLK (M_TOK/64)                 // 256 blocks / chunks of 64 tokens
#define NC (Dd/64)                      // 64 k-chunks
#define IDX_OFF   0
#define TOP1_OFF  (M_TOK*Ee)            // 1048576
#define PROBS_OFF (TOP1_OFF + M_TOK)    // 1064960
#define AUX_OFF   (PROBS_OFF + M_TOK*Ee)// 2113536
#define ND_OFF    (AUX_OFF + 1)         // 2113537

// ---------------- K1: logits GEMM + softmax + argmax + chunk stats ----------
__global__ __launch_bounds__(256) void k1_router(
    const float* __restrict__ H, const float* __restrict__ Wm,
    const float* __restrict__ bias, float* __restrict__ out,
    int* __restrict__ cnt_ws, float* __restrict__ pi_ws,
    int* __restrict__ eid_ws) {
  __shared__ float hs[64][64];          // 16 KB h-tile [token][k]
  const int tid  = threadIdx.x;
  const int wave = tid >> 6;
  const int lane = tid & 63;            // lane == expert
  const int blk  = blockIdx.x;
  const int tb   = blk * 64;            // first token of this block
  const int wrow = wave * 16;           // first token row of this wave

  float acc[16];
#pragma unroll
  for (int t = 0; t < 16; ++t) acc[t] = 0.f;

  float* hsflat = &hs[0][0];
  float4 st[4];

#define STAGE_LOAD(cidx) {                                                   \
    const int c64_ = (cidx) * 64;                                            \
    _Pragma("unroll")                                                        \
    for (int i = 0; i < 4; ++i) {                                            \
      const int q = i * 256 + tid;                                           \
      st[i] = *(const float4*)(H + (size_t)(tb + (q >> 4)) * Dd + c64_ +     \
                               (q & 15) * 4);                                \
    } }

  STAGE_LOAD(0);

  for (int c = 0; c < NC; ++c) {
    __syncthreads();                    // all waves done reading prev tile
#pragma unroll
    for (int i = 0; i < 4; ++i) {       // regs -> LDS
      const int q = i * 256 + tid;
      *(float4*)(hsflat + q * 4) = st[i];
    }
    if (c + 1 < NC) STAGE_LOAD(c + 1);  // prefetch next chunk into regs
    __syncthreads();                    // tile visible to all

    const float* Wc = Wm + (size_t)(c * 64) * Ee;
#pragma unroll
    for (int kk = 0; kk < 4; ++kk) {
      float wreg[16];
#pragma unroll
      for (int j = 0; j < 16; ++j) wreg[j] = Wc[(size_t)(kk * 16 + j) * Ee + lane];
#pragma unroll
      for (int t = 0; t < 16; ++t) {
        const float4* hp = (const float4*)(hsflat + (wrow + t) * 64 + kk * 16);
#pragma unroll
        for (int j = 0; j < 4; ++j) {
          const float4 hv = hp[j];      // broadcast ds_read_b128 (uniform addr)
          acc[t] = fmaf(hv.x, wreg[4*j+0], acc[t]);
          acc[t] = fmaf(hv.y, wreg[4*j+1], acc[t]);
          acc[t] = fmaf(hv.z, wreg[4*j+2], acc[t]);
          acc[t] = fmaf(hv.w, wreg[4*j+3], acc[t]);
        }
      }
    }
  }

  // ---------------- softmax / argmax / stats epilogue ----------------
  __syncthreads();                      // hs reused below
  const float bl = bias[lane];
  int   cnt   = 0;
  float pisum = 0.f;

  for (int t = 0; t < 16; ++t) {
    const int tok = tb + wrow + t;
    const float v = acc[t] + bl;
    float m = v; int mi = lane;
#pragma unroll
    for (int off = 32; off >= 1; off >>= 1) {   // max + first-index argmax
      const float ov = __shfl_xor(m, off);
      const int   oi = __shfl_xor(mi, off);
      if (ov > m || (ov == m && oi < mi)) { m = ov; mi = oi; }
    }
    const float ex = __expf(v - m);
    float ssum = ex;
#pragma unroll
    for (int off = 32; off >= 1; off >>= 1) ssum += __shfl_xor(ssum, off);
    const float inv = 1.0f / ssum;
    const float p = ex * inv;
    out[(size_t)PROBS_OFF + (size_t)tok * Ee + lane] = p;
    if (lane == 0) {
      out[TOP1_OFF + tok] = inv;        // max prob = exp(0)/sum = 1/sum
      eid_ws[tok] = mi;
    }
    cnt   += (mi == lane) ? 1 : 0;
    pisum += p;
  }

  // combine per-wave counts / pi partials across the 4 waves
  int*   cshare = (int*)&hs[0][0];      // [4][64] ints
  float* pshare = &hs[4][0];            // [4][64] floats
  cshare[wave * 64 + lane] = cnt;
  pshare[wave * 64 + lane] = pisum;
  __syncthreads();
  if (tid < 64) {
    const int   ct = cshare[tid] + cshare[64 + tid] + cshare[128 + tid] + cshare[192 + tid];
    const float pp = pshare[tid] + pshare[64 + tid] + pshare[128 + tid] + pshare[192 + tid];
    cnt_ws[blk * 64 + tid] = ct;
    pi_ws [blk * 64 + tid] = pp;
  }
}

// ---------------- K3: capacity mask + one-hot write + aux/dropped -----------
__global__ __launch_bounds__(64) void k3_indices(
    const int* __restrict__ cnt_ws, const float* __restrict__ pi_ws,
    const int* __restrict__ eid_ws, float* __restrict__ out) {
  __shared__ float tile[64][64];
  const int g    = blockIdx.x;          // chunk id (64 tokens)
  const int lane = threadIdx.x;
  const int b    = g >> 5;              // 32 chunks per batch row
  const int c    = g & 31;
  const int tok  = g * 64 + lane;
  const int e    = eid_ws[tok];

  // local rank of this token among same-expert tokens in the chunk
  unsigned long long mymask = 0ull;
  for (int j = 0; j < 64; ++j) {
    const int ej = __shfl(e, j);
    const unsigned long long bal = __ballot(ej == e);
    if (j == lane) mymask = bal;
  }
  const int lrank = __popcll(mymask & ((1ull << lane) - 1ull));

  int prefix = 0;
  for (int cc = 0; cc < c; ++cc) prefix += cnt_ws[(b * 32 + cc) * 64 + e];

  const float keep = (prefix + lrank < CAP) ? 1.0f : 0.0f;

#pragma unroll
  for (int j = 0; j < 64; ++j) tile[j][lane] = 0.f;
  __syncthreads();
  tile[lane][e] = keep;
  __syncthreads();

  float4*       og = (float4*)(out + (size_t)g * 64 * 64);
  const float4* ts = (const float4*)&tile[0][0];
#pragma unroll
  for (int i = 0; i < 16; ++i) og[i * 64 + lane] = ts[i * 64 + lane];

  if (g == 0) {                         // aux loss + num_dropped (deterministic)
    float auxsum = 0.f; int dropped = 0;
    for (int bb = 0; bb < 8; ++bb) {
      int tot = 0; float psum = 0.f;
      for (int cc = 0; cc < 32; ++cc) {
        tot  += cnt_ws[(bb * 32 + cc) * 64 + lane];
        psum += pi_ws [(bb * 32 + cc) * 64 + lane];
      }
      dropped += (tot > CAP) ? (tot - CAP) : 0;
      const float fi = (float)((tot < CAP) ? tot : CAP) * (1.0f / (float)Ss);
      const float pi = psum * (1.0f / (float)Ss);
      float fp = fi * pi;
#pragma unroll
      for (int off = 32; off >= 1; off >>= 1) fp += __shfl_xor(fp, off);
      auxsum += fp;                     // Σ_e fi·pi for batch bb (all lanes)
    }
#pragma unroll
    for (int off = 32; off >= 1; off >>= 1) dropped += __shfl_xor(dropped, off);
    if (lane == 0) {
      out[AUX_OFF] = (float)Ee * auxsum / (float)Bb;
      out[ND_OFF]  = (float)dropped;
    }
  }
}

extern "C" void kernel_launch(void* const* d_in, const int* in_sizes, int n_in,
                              void* d_out, int out_size, void* d_ws, size_t ws_size,
                              hipStream_t stream) {
  const float* H    = (const float*)d_in[0];
  const float* Wm   = (const float*)d_in[1];
  const float* bias = (const float*)d_in[2];
  float* out = (float*)d_out;
  int*   cnt_ws = (int*)d_ws;                           // 256*64 int  = 64 KB
  float* pi_ws  = (float*)((char*)d_ws + 65536);        // 256*64 f32  = 64 KB
  int*   eid_ws = (int*)((char*)d_ws + 131072);         // 16384 int   = 64 KB

  hipLaunchKernelGGL(k1_router, dim3(NBLK), dim3(256), 0, stream,
                     H, Wm, bias, out, cnt_ws, pi_ws, eid_ws);
  hipLaunchKernelGGL(k3_indices, dim3(NBLK), dim3(64), 0, stream,
                     cnt_ws, pi_ws, eid_ws, out);
}

// Round 2
// 342.146 us; speedup vs baseline: 2.6083x; 2.6083x over previous
//
#include <hip/hip_runtime.h>
#include <hip/hip_bf16.h>
#include <stdint.h>

#define Bb 8
#define Ss 2048
#define Dd 4096
#define Ee 64
#define CAP 40
#define M_TOK (Bb*Ss)                   // 16384 tokens
#define NBLK (M_TOK/64)                 // 256 blocks / chunks of 64 tokens
#define NC (Dd/64)                      // 64 k-chunks
#define TOP1_OFF  (M_TOK*Ee)            // 1048576
#define PROBS_OFF (TOP1_OFF + M_TOK)    // 1064960
#define AUX_OFF   (PROBS_OFF + M_TOK*Ee)// 2113536
#define ND_OFF    (AUX_OFF + 1)         // 2113537

// ---------------- K1: logits GEMM + softmax + argmax + chunk stats ----------
// lane = token, wave = 8-expert slice. W via scalar loads (wave-uniform).
__global__ __launch_bounds__(512) void k1_router(
    const float* __restrict__ H, const float* __restrict__ Wm,
    const float* __restrict__ bias, float* __restrict__ out,
    int* __restrict__ cnt_ws, float* __restrict__ pi_ws,
    int* __restrict__ eid_ws) {
  __shared__ float smem[2 * 4096 + 2 * 512]; // 2 h-tiles (32KB) + cnt/pi share (4KB)
  const int tid = threadIdx.x;
  const int wv  = tid >> 6;
  const int ln  = tid & 63;              // lane == token-within-block
  const int eb  = __builtin_amdgcn_readfirstlane(wv * 8);  // wave's expert base
  const int tb  = blockIdx.x * 64;

  float acc[8];
#pragma unroll
  for (int j = 0; j < 8; ++j) acc[j] = 0.f;

  // LDS float4-slot (tok, s) holds H[tb+tok][c*64 + (s^(tok&15))*4 .. +3]
  float4 st[2];
#define STAGE(c) {                                                           \
    _Pragma("unroll")                                                        \
    for (int i = 0; i < 2; ++i) {                                            \
      const int q = i * 512 + tid;                                           \
      const int tok = q >> 4, s = q & 15;                                    \
      const int p = s ^ (tok & 15);                                          \
      st[i] = *(const float4*)(H + (size_t)(tb + tok) * Dd + (c) * 64 + p * 4); \
    } }

  STAGE(0);
  int cur = 0;
  for (int c = 0; c < NC; ++c) {
    float* buf = smem + cur * 4096;
#pragma unroll
    for (int i = 0; i < 2; ++i) {        // regs -> LDS (this chunk)
      const int q = i * 512 + tid;
      ((float4*)buf)[q] = st[i];
    }
    if (c + 1 < NC) STAGE(c + 1);        // prefetch next chunk into regs
    __syncthreads();                     // tile ready (single barrier per chunk)

    const float4* hrow = (const float4*)buf + ln * 16;
    const float*  Wc   = Wm + (size_t)c * 64 * Ee + eb;
#pragma unroll
    for (int k4 = 0; k4 < 16; ++k4) {
      const float4 hv = hrow[k4 ^ (ln & 15)];   // conflict-free (XOR swizzle)
      const float h4[4] = {hv.x, hv.y, hv.z, hv.w};
#pragma unroll
      for (int kk = 0; kk < 4; ++kk) {
        const float* Wk = Wc + (size_t)(k4 * 4 + kk) * Ee;  // uniform -> s_load
        const float h = h4[kk];
#pragma unroll
        for (int j = 0; j < 8; ++j) acc[j] = fmaf(h, Wk[j], acc[j]);
      }
    }
    cur ^= 1;
  }

  // ---------------- epilogue: transpose via padded LDS, softmax ------------
  __syncthreads();                       // all compute done; reuse tile space
  float* lg = smem;                      // [64][65] logits, 4160 floats
#pragma unroll
  for (int j = 0; j < 8; ++j) lg[ln * 65 + eb + j] = acc[j] + bias[eb + j];
  int*   cshare = (int*)(smem + 8192);   // [8][64]
  float* pshare = smem + 8192 + 512;     // [8][64]
  __syncthreads();

  int cnt = 0; float pisum = 0.f;
  for (int t8 = 0; t8 < 8; ++t8) {       // wave handles 8 tokens, lane=expert
    const int t   = wv * 8 + t8;
    const int tok = tb + t;
    const float v = lg[t * 65 + ln];
    float m = v; int mi = ln;
#pragma unroll
    for (int off = 32; off >= 1; off >>= 1) {   // max + first-index argmax
      const float ov = __shfl_xor(m, off);
      const int   oi = __shfl_xor(mi, off);
      if (ov > m || (ov == m && oi < mi)) { m = ov; mi = oi; }
    }
    const float ex = __expf(v - m);
    float ssum = ex;
#pragma unroll
    for (int off = 32; off >= 1; off >>= 1) ssum += __shfl_xor(ssum, off);
    const float inv = 1.0f / ssum;
    const float p = ex * inv;
    out[(size_t)PROBS_OFF + (size_t)tok * Ee + ln] = p;
    if (ln == 0) {
      out[TOP1_OFF + tok] = inv;         // max prob = 1/sum
      eid_ws[tok] = mi;
    }
    cnt   += (mi == ln) ? 1 : 0;
    pisum += p;
  }

  cshare[wv * 64 + ln] = cnt;
  pshare[wv * 64 + ln] = pisum;
  __syncthreads();
  if (tid < 64) {
    int ct = 0; float pp = 0.f;
#pragma unroll
    for (int w = 0; w < 8; ++w) { ct += cshare[w * 64 + tid]; pp += pshare[w * 64 + tid]; }
    cnt_ws[blockIdx.x * 64 + tid] = ct;
    pi_ws [blockIdx.x * 64 + tid] = pp;
  }
}

// ---------------- K3: capacity mask + one-hot write + aux/dropped -----------
__global__ __launch_bounds__(64) void k3_indices(
    const int* __restrict__ cnt_ws, const float* __restrict__ pi_ws,
    const int* __restrict__ eid_ws, float* __restrict__ out) {
  __shared__ float tile[64][64];
  const int g    = blockIdx.x;          // chunk id (64 tokens)
  const int lane = threadIdx.x;
  const int b    = g >> 5;              // 32 chunks per batch row
  const int c    = g & 31;
  const int tok  = g * 64 + lane;
  const int e    = eid_ws[tok];

  // local rank of this token among same-expert tokens in the chunk
  unsigned long long mymask = 0ull;
  for (int j = 0; j < 64; ++j) {
    const int ej = __shfl(e, j);
    const unsigned long long bal = __ballot(ej == e);
    if (j == lane) mymask = bal;
  }
  const int lrank = __popcll(mymask & ((1ull << lane) - 1ull));

  int prefix = 0;
  for (int cc = 0; cc < c; ++cc) prefix += cnt_ws[(b * 32 + cc) * 64 + e];

  const float keep = (prefix + lrank < CAP) ? 1.0f : 0.0f;

#pragma unroll
  for (int j = 0; j < 64; ++j) tile[j][lane] = 0.f;
  __syncthreads();
  tile[lane][e] = keep;
  __syncthreads();

  float4*       og = (float4*)(out + (size_t)g * 64 * 64);
  const float4* ts = (const float4*)&tile[0][0];
#pragma unroll
  for (int i = 0; i < 16; ++i) og[i * 64 + lane] = ts[i * 64 + lane];

  if (g == 0) {                         // aux loss + num_dropped (deterministic)
    float auxsum = 0.f; int dropped = 0;
    for (int bb = 0; bb < 8; ++bb) {
      int tot = 0; float psum = 0.f;
      for (int cc = 0; cc < 32; ++cc) {
        tot  += cnt_ws[(bb * 32 + cc) * 64 + lane];
        psum += pi_ws [(bb * 32 + cc) * 64 + lane];
      }
      dropped += (tot > CAP) ? (tot - CAP) : 0;
      const float fi = (float)((tot < CAP) ? tot : CAP) * (1.0f / (float)Ss);
      const float pi = psum * (1.0f / (float)Ss);
      float fp = fi * pi;
#pragma unroll
      for (int off = 32; off >= 1; off >>= 1) fp += __shfl_xor(fp, off);
      auxsum += fp;                     // Σ_e fi·pi for batch bb
    }
#pragma unroll
    for (int off = 32; off >= 1; off >>= 1) dropped += __shfl_xor(dropped, off);
    if (lane == 0) {
      out[AUX_OFF] = (float)Ee * auxsum / (float)Bb;
      out[ND_OFF]  = (float)dropped;
    }
  }
}

extern "C" void kernel_launch(void* const* d_in, const int* in_sizes, int n_in,
                              void* d_out, int out_size, void* d_ws, size_t ws_size,
                              hipStream_t stream) {
  const float* H    = (const float*)d_in[0];
  const float* Wm   = (const float*)d_in[1];
  const float* bias = (const float*)d_in[2];
  float* out = (float*)d_out;
  int*   cnt_ws = (int*)d_ws;                           // 256*64 int  = 64 KB
  float* pi_ws  = (float*)((char*)d_ws + 65536);        // 256*64 f32  = 64 KB
  int*   eid_ws = (int*)((char*)d_ws + 131072);         // 16384 int   = 64 KB

  hipLaunchKernelGGL(k1_router, dim3(NBLK), dim3(512), 0, stream,
                     H, Wm, bias, out, cnt_ws, pi_ws, eid_ws);
  hipLaunchKernelGGL(k3_indices, dim3(NBLK), dim3(64), 0, stream,
                     cnt_ws, pi_ws, eid_ws, out);
}

// Round 3
// 118.785 us; speedup vs baseline: 7.5129x; 2.8804x over previous
//
#include <hip/hip_runtime.h>
#include <stdint.h>

#define Bb 8
#define Ss 2048
#define Dd 4096
#define Ee 64
#define CAP 40
#define M_TOK (Bb*Ss)                   // 16384 tokens
#define TPB 32                          // tokens per k1 block
#define NB1 (M_TOK/TPB)                 // 512 k1 blocks
#define NCH (Dd/64)                     // 64 K-chunks of 64
#define NCHK (M_TOK/64)                 // 256 chunks for k3
#define TOP1_OFF  (M_TOK*Ee)            // 1048576
#define PROBS_OFF (TOP1_OFF + M_TOK)    // 1064960
#define AUX_OFF   (PROBS_OFF + M_TOK*Ee)// 2113536
#define ND_OFF    (AUX_OFF + 1)         // 2113537
#define ROWB 272                        // LDS bytes per token row: [hi 128][lo 128][pad 16]
#define BUFB (TPB*ROWB)                 // 8704

typedef __attribute__((ext_vector_type(8))) short short8;
typedef __attribute__((ext_vector_type(4))) float f32x4;

__device__ __forceinline__ ushort f2bf(float x) {   // fp32 -> bf16 bits, RNE
  union { float f; unsigned u; } v; v.f = x;
  return (ushort)((v.u + 0x7fffu + ((v.u >> 16) & 1u)) >> 16);
}
__device__ __forceinline__ float bf2f(ushort b) {
  union { float f; unsigned u; } v; v.u = ((unsigned)b) << 16; return v.f;
}

// ---------------- k0: W [k][e] fp32 -> ws hi/lo bf16 transposed [e][k] ------
__global__ __launch_bounds__(256) void k0_wsplit(const float* __restrict__ W,
                                                 ushort* __restrict__ wh) {
  ushort* wl = wh + (size_t)Dd * Ee;
  const int l  = threadIdx.x & 63;            // lane = expert
  const int wv = threadIdx.x >> 6;
  const int kb = blockIdx.x * 64 + wv * 16;   // 16 k-rows per wave
  ushort hi[16], lo[16];
#pragma unroll
  for (int j = 0; j < 16; ++j) {              // coalesced: 64 lanes read row k
    const float x = W[(size_t)(kb + j) * Ee + l];
    const ushort h = f2bf(x);
    hi[j] = h;
    lo[j] = f2bf(x - bf2f(h));                // x - hi exact (Sterbenz)
  }
  const size_t o = (size_t)l * Dd + kb;
  short8 h0, h1, l0, l1;
#pragma unroll
  for (int j = 0; j < 8; ++j) {
    h0[j] = (short)hi[j]; h1[j] = (short)hi[8 + j];
    l0[j] = (short)lo[j]; l1[j] = (short)lo[8 + j];
  }
  *(short8*)(wh + o) = h0; *(short8*)(wh + o + 8) = h1;
  *(short8*)(wl + o) = l0; *(short8*)(wl + o + 8) = l1;
}

// ---------------- k1: MFMA logits + softmax + argmax + chunk stats ----------
__global__ __launch_bounds__(256) void k1_router(
    const float* __restrict__ H, const ushort* __restrict__ wh,
    const float* __restrict__ bias, float* __restrict__ out,
    int* __restrict__ cnt_ws, float* __restrict__ pi_ws,
    int* __restrict__ eid_ws) {
  __shared__ char lds[2 * BUFB];               // 17408 B, epilogue reuses
  const int tid = threadIdx.x;
  const int wv  = tid >> 6, l = tid & 63;
  const int tb  = blockIdx.x * TPB;
  const ushort* wlp = wh + (size_t)Dd * Ee;

  f32x4 acc0 = {0.f,0.f,0.f,0.f}, acc1 = {0.f,0.f,0.f,0.f};

  float4 st0, st1;                             // staged H (2 float4/thread)
#define PREF(c) {                                                             \
    st0 = *(const float4*)(H + (size_t)(tb + (tid >> 4)) * Dd + (c) * 64 +    \
                           (tid & 15) * 4);                                   \
    st1 = *(const float4*)(H + (size_t)(tb + 16 + (tid >> 4)) * Dd + (c) * 64 \
                           + (tid & 15) * 4); }

#define WRT(stv, tok_, f4_) {                                                 \
    const ushort hx = f2bf(stv.x), hy = f2bf(stv.y),                          \
                 hz = f2bf(stv.z), hw = f2bf(stv.w);                          \
    uint2 hp, lp;                                                             \
    hp.x = (unsigned)hx | ((unsigned)hy << 16);                               \
    hp.y = (unsigned)hz | ((unsigned)hw << 16);                               \
    lp.x = (unsigned)f2bf(stv.x - bf2f(hx)) |                                 \
           ((unsigned)f2bf(stv.y - bf2f(hy)) << 16);                          \
    lp.y = (unsigned)f2bf(stv.z - bf2f(hz)) |                                 \
           ((unsigned)f2bf(stv.w - bf2f(hw)) << 16);                          \
    *(uint2*)(buf + (tok_) * ROWB + (f4_) * 8) = hp;                          \
    *(uint2*)(buf + (tok_) * ROWB + 128 + (f4_) * 8) = lp; }

  PREF(0);
  const size_t boff = (size_t)(wv * 16 + (l & 15)) * Dd + (l >> 4) * 8;
  const ushort* bh_p = wh  + boff;
  const ushort* bl_p = wlp + boff;
  const int arow = (l & 15) * ROWB + (l >> 4) * 16;

  int cur = 0;
  for (int c = 0; c < NCH; ++c) {
    char* buf = lds + cur * BUFB;
    WRT(st0, (tid >> 4), (tid & 15));
    WRT(st1, (16 + (tid >> 4)), (tid & 15));
    if (c + 1 < NCH) PREF(c + 1);
    __syncthreads();                           // tile ready (1 barrier/chunk)
    const char* ab = buf + arow;
#pragma unroll
    for (int kk = 0; kk < 2; ++kk) {
      const short8 a0h = *(const short8*)(ab + kk * 64);
      const short8 a0l = *(const short8*)(ab + 128 + kk * 64);
      const short8 a1h = *(const short8*)(ab + 16 * ROWB + kk * 64);
      const short8 a1l = *(const short8*)(ab + 16 * ROWB + 128 + kk * 64);
      const short8 bh  = *(const short8*)(bh_p + c * 64 + kk * 32);
      const short8 bl  = *(const short8*)(bl_p + c * 64 + kk * 32);
      acc0 = __builtin_amdgcn_mfma_f32_16x16x32_bf16(a0h, bh, acc0, 0, 0, 0);
      acc0 = __builtin_amdgcn_mfma_f32_16x16x32_bf16(a0h, bl, acc0, 0, 0, 0);
      acc0 = __builtin_amdgcn_mfma_f32_16x16x32_bf16(a0l, bh, acc0, 0, 0, 0);
      acc0 = __builtin_amdgcn_mfma_f32_16x16x32_bf16(a0l, bl, acc0, 0, 0, 0);
      acc1 = __builtin_amdgcn_mfma_f32_16x16x32_bf16(a1h, bh, acc1, 0, 0, 0);
      acc1 = __builtin_amdgcn_mfma_f32_16x16x32_bf16(a1h, bl, acc1, 0, 0, 0);
      acc1 = __builtin_amdgcn_mfma_f32_16x16x32_bf16(a1l, bh, acc1, 0, 0, 0);
      acc1 = __builtin_amdgcn_mfma_f32_16x16x32_bf16(a1l, bl, acc1, 0, 0, 0);
    }
    cur ^= 1;
  }

  // ------- epilogue: C-frag -> LDS [32][65] fp32 -> shuffle softmax --------
  __syncthreads();
  float* lg = (float*)lds;
  const int col = wv * 16 + (l & 15);
  const int r0  = (l >> 4) * 4;
#pragma unroll
  for (int r = 0; r < 4; ++r) {
    lg[(r0 + r) * 65 + col]      = acc0[r];    // tokens 0-15
    lg[(16 + r0 + r) * 65 + col] = acc1[r];    // tokens 16-31
  }
  int*   csh = (int*)(lds + 8448);
  float* psh = (float*)(lds + 8448 + 1024);
  __syncthreads();

  int cnt = 0; float pis = 0.f;
  const float bl_ = bias[l];
#pragma unroll
  for (int i = 0; i < 8; ++i) {                // wave owns 8 rows, lane=expert
    const int t = wv * 8 + i, tok = tb + t;
    const float v = lg[t * 65 + l] + bl_;
    float m = v; int mi = l;
#pragma unroll
    for (int off = 32; off >= 1; off >>= 1) {  // max + first-index argmax
      const float ov = __shfl_xor(m, off);
      const int   oi = __shfl_xor(mi, off);
      if (ov > m || (ov == m && oi < mi)) { m = ov; mi = oi; }
    }
    const float ex = __expf(v - m);
    float ssum = ex;
#pragma unroll
    for (int off = 32; off >= 1; off >>= 1) ssum += __shfl_xor(ssum, off);
    const float inv = 1.0f / ssum;
    const float p = ex * inv;
    out[(size_t)PROBS_OFF + (size_t)tok * Ee + l] = p;
    if (l == 0) {
      out[TOP1_OFF + tok] = inv;               // max prob = 1/sum
      eid_ws[tok] = mi;
    }
    cnt += (mi == l) ? 1 : 0;
    pis += p;
  }
  csh[wv * 64 + l] = cnt;
  psh[wv * 64 + l] = pis;
  __syncthreads();
  if (tid < 64) {
    const int   ct = csh[tid] + csh[64 + tid] + csh[128 + tid] + csh[192 + tid];
    const float pp = psh[tid] + psh[64 + tid] + psh[128 + tid] + psh[192 + tid];
    cnt_ws[blockIdx.x * 64 + tid] = ct;
    pi_ws [blockIdx.x * 64 + tid] = pp;
  }
}

// ---------------- k3: capacity mask + one-hot write + aux/dropped -----------
__global__ __launch_bounds__(64) void k3_indices(
    const int* __restrict__ cnt_ws, const float* __restrict__ pi_ws,
    const int* __restrict__ eid_ws, float* __restrict__ out) {
  __shared__ float tile[64][64];
  const int g    = blockIdx.x;                 // 64-token chunk
  const int lane = threadIdx.x;
  const int b    = g >> 5;                     // 32 chunks per batch row
  const int c    = g & 31;
  const int tok  = g * 64 + lane;
  const int e    = eid_ws[tok];

  unsigned long long mymask = 0ull;            // rank within chunk
  for (int j = 0; j < 64; ++j) {
    const int ej = __shfl(e, j);
    const unsigned long long bal = __ballot(ej == e);
    if (j == lane) mymask = bal;
  }
  const int lrank = __popcll(mymask & ((1ull << lane) - 1ull));

  int prefix = 0;                              // 2 k1-blocks (32 tok) per chunk
  for (int cc = 0; cc < 2 * c; ++cc) prefix += cnt_ws[(b * 64 + cc) * 64 + e];

  const float keep = (prefix + lrank < CAP) ? 1.0f : 0.0f;

#pragma unroll
  for (int j = 0; j < 64; ++j) tile[j][lane] = 0.f;
  __syncthreads();
  tile[lane][e] = keep;
  __syncthreads();

  float4*       og = (float4*)(out + (size_t)g * 64 * 64);
  const float4* ts = (const float4*)&tile[0][0];
#pragma unroll
  for (int i = 0; i < 16; ++i) og[i * 64 + lane] = ts[i * 64 + lane];

  if (g == 0) {                                // aux loss + num_dropped
    float auxsum = 0.f; int dropped = 0;
    for (int bb = 0; bb < 8; ++bb) {
      int tot = 0; float psum = 0.f;
      for (int cc = 0; cc < 64; ++cc) {
        tot  += cnt_ws[(bb * 64 + cc) * 64 + lane];
        psum += pi_ws [(bb * 64 + cc) * 64 + lane];
      }
      dropped += (tot > CAP) ? (tot - CAP) : 0;
      const float fi = (float)((tot < CAP) ? tot : CAP) * (1.0f / (float)Ss);
      const float pi = psum * (1.0f / (float)Ss);
      float fp = fi * pi;
#pragma unroll
      for (int off = 32; off >= 1; off >>= 1) fp += __shfl_xor(fp, off);
      auxsum += fp;
    }
#pragma unroll
    for (int off = 32; off >= 1; off >>= 1) dropped += __shfl_xor(dropped, off);
    if (lane == 0) {
      out[AUX_OFF] = (float)Ee * auxsum / (float)Bb;
      out[ND_OFF]  = (float)dropped;
    }
  }
}

extern "C" void kernel_launch(void* const* d_in, const int* in_sizes, int n_in,
                              void* d_out, int out_size, void* d_ws, size_t ws_size,
                              hipStream_t stream) {
  const float* H    = (const float*)d_in[0];
  const float* Wm   = (const float*)d_in[1];
  const float* bias = (const float*)d_in[2];
  float* out = (float*)d_out;
  ushort* wsp   = (ushort*)d_ws;                          // 1 MB hi+lo bf16
  int*    cnt_ws = (int*)  ((char*)d_ws + (1u << 20));    // 512*64*4 = 128 KB
  float*  pi_ws  = (float*)((char*)d_ws + (1u << 20) + (128u << 10));
  int*    eid_ws = (int*)  ((char*)d_ws + (1u << 20) + (256u << 10));

  hipLaunchKernelGGL(k0_wsplit, dim3(Dd / 64), dim3(256), 0, stream, Wm, wsp);
  hipLaunchKernelGGL(k1_router, dim3(NB1), dim3(256), 0, stream,
                     H, wsp, bias, out, cnt_ws, pi_ws, eid_ws);
  hipLaunchKernelGGL(k3_indices, dim3(NCHK), dim3(64), 0, stream,
                     cnt_ws, pi_ws, eid_ws, out);
}